// Round 1
// baseline (447.905 us; speedup 1.0000x reference)
//
#include <hip/hip_runtime.h>
#include <stdint.h>
#include <math.h>

typedef unsigned int u32;
typedef unsigned long long u64;

#define NBUCKET 4096

__device__ __forceinline__ u32 f2key(float f){
  u32 b = __float_as_uint(f);
  return (b & 0x80000000u) ? ~b : (b | 0x80000000u);
}

// D table: Dtab[x] = 1/log2(1+x), x in [1, B+1]; Dtab[0] unused.
__global__ void k_dtab(float* __restrict__ Dtab, int n){
  int x = blockIdx.x*256 + threadIdx.x;
  if (x < n) Dtab[x] = (x==0) ? 0.0f : (float)(1.0/log2(1.0 + (double)x));
}

// Bucket histogram + P counts
__global__ void k_hist(const float* __restrict__ scores, const int* __restrict__ labels,
                       int B, int NC, u32* __restrict__ bhist, u32* __restrict__ Pcnt){
  int t = blockIdx.x*256 + threadIdx.x;
  if (t >= B*NC) return;
  int b = t / NC, c = t % NC;
  float v = scores[t];
  int isPos = (labels[b] == c);
  u32 u = f2key(v);
  u32 bucket = u >> 20;
  int pi = c*2 + (isPos ? 0 : 1);   // part0=pos, part1=neg
  atomicAdd(&bhist[(size_t)pi*NBUCKET + bucket], 1u);
  if (isPos) atomicAdd(&Pcnt[c], 1u);
}

// Exclusive scan of 4096 bins per (class,part); also init cursors.
__global__ void k_scan(const u32* __restrict__ bhist, u32* __restrict__ bstart, u32* __restrict__ bcursor){
  __shared__ u32 sc[1024];
  int pi = blockIdx.x, tid = threadIdx.x;
  const u32* h = bhist + (size_t)pi*NBUCKET;
  u32 v0 = h[tid*4+0], v1 = h[tid*4+1], v2 = h[tid*4+2], v3 = h[tid*4+3];
  u32 tot = v0+v1+v2+v3;
  sc[tid] = tot; __syncthreads();
  for (int off=1; off<1024; off<<=1){
    u32 t2 = (tid>=off) ? sc[tid-off] : 0u;
    __syncthreads();
    sc[tid] += t2;
    __syncthreads();
  }
  u32 run = sc[tid] - tot;  // exclusive prefix for this thread's 4 bins
  u32* bs = bstart  + (size_t)pi*(NBUCKET+1);
  u32* bc = bcursor + (size_t)pi*NBUCKET;
  bs[tid*4+0]=run; bc[tid*4+0]=run; run+=v0;
  bs[tid*4+1]=run; bc[tid*4+1]=run; run+=v1;
  bs[tid*4+2]=run; bc[tid*4+2]=run; run+=v2;
  bs[tid*4+3]=run; bc[tid*4+3]=run; run+=v3;
  if (tid==1023) bs[NBUCKET]=run;
}

// Scatter packed keys (key<<32 | orig_index) into bucket-grouped order.
__global__ void k_scatter(const float* __restrict__ scores, const int* __restrict__ labels,
                          int B, int NC, u32* __restrict__ bcursor, u64* __restrict__ keyArr){
  int t = blockIdx.x*256 + threadIdx.x;
  if (t >= B*NC) return;
  int b = t / NC, c = t % NC;
  float v = scores[t];
  int isPos = (labels[b] == c);
  u32 u = f2key(v);
  u32 bucket = u >> 20;
  int pi = c*2 + (isPos ? 0 : 1);
  u32 slot = atomicAdd(&bcursor[(size_t)pi*NBUCKET + bucket], 1u);
  keyArr[(size_t)pi*B + slot] = ((u64)u << 32) | (u32)b;
}

// Exact rank within bucket (deterministic via unique packed keys) -> sorted arrays.
__global__ void k_rank(const u64* __restrict__ keyArr, const u32* __restrict__ bstart,
                       const u32* __restrict__ Pcnt, int B,
                       float* __restrict__ sPos, float* __restrict__ sNeg){
  int pi = blockIdx.y; int c = pi >> 1; int part = pi & 1;
  u32 P = Pcnt[c];
  u32 cnt = part ? ((u32)B - P) : P;
  u32 t = blockIdx.x*256 + threadIdx.x;
  if (t >= cnt) return;
  const u64* ka = keyArr + (size_t)pi*B;
  u64 K = ka[t];
  u32 bucket = (u32)(K >> 52);
  const u32* bs = bstart + (size_t)pi*(NBUCKET+1);
  u32 lo = bs[bucket], hi = bs[bucket+1];
  u32 r = lo;
  for (u32 x=lo; x<hi; ++x) r += (ka[x] < K) ? 1u : 0u;
  u32 u = (u32)(K >> 32);
  u32 bits = (u & 0x80000000u) ? (u & 0x7fffffffu) : ~u;
  float val = __uint_as_float(bits);
  if (part == 0) sPos[(size_t)c*B + (P-1u-r)] = val;   // descending
  else           sNeg[(size_t)c*B + r]        = val;   // ascending
}

// Per-class: Cconst, suffix sums Sl -> scaled coefficients A', B'.
__global__ void k_pre(const float* __restrict__ sPos, const u32* __restrict__ Pcnt,
                      const float* __restrict__ Dtab, int B,
                      float* __restrict__ Aarr, float* __restrict__ Barr,
                      double* __restrict__ Cconst){
  __shared__ double red[1024];
  int c = blockIdx.x, tid = threadIdx.x;
  u32 P = Pcnt[c]; u32 N = (u32)B - P;
  if (P==0 || N==0){ if (tid==0) Cconst[c]=1.0; return; }
  double s=0.0;
  for (u32 i=1+tid; i<=P; i+=1024) s += (double)Dtab[i];
  red[tid]=s; __syncthreads();
  for (int off=512; off>0; off>>=1){ if (tid<off) red[tid]+=red[tid+off]; __syncthreads(); }
  double Cc = red[0];
  if (tid==0) Cconst[c]=Cc;
  const float* sp = sPos + (size_t)c*B;
  double PN = (double)P*(double)N;
  double ca = -2.0*Cc/PN;
  float* A  = Aarr + (size_t)c*(B+1);
  float* Bc = Barr + (size_t)c*(B+1);
  for (u32 j=tid; j<=P; j+=1024){
    double Sl=0.0;
    for (u32 k=j; k<P; ++k) Sl += (double)sp[k];
    A[j]  = (float)(ca*Sl);
    Bc[j] = (float)(2.0*Cc*(double)(P-j)/PN);
  }
}

// Main: per negative m, argmax over j of fma(B'[j],sm,A'[j]) + Dtab[m+1+j]
__global__ void k_main(const float* __restrict__ sNeg, const u32* __restrict__ Pcnt,
                       const float* __restrict__ Dtab, const float* __restrict__ Aarr,
                       const float* __restrict__ Barr, int B,
                       u32* __restrict__ optHist, double* __restrict__ partials){
  __shared__ double r1[256], r2[256];
  int c = blockIdx.y;
  u32 P = Pcnt[c]; u32 N = (u32)B - P;
  int m = blockIdx.x*256 + threadIdx.x;
  double s1=0.0, s2=0.0;
  if (P>0u && N>0u && m < (int)N){
    float sm = sNeg[(size_t)c*B + m];
    const float* A  = Aarr + (size_t)c*(B+1);
    const float* Bc = Barr + (size_t)c*(B+1);
    const float* Dt = Dtab + m + 1;
    float best = -3.402823466e38f; u32 bj = 0u;
    int Pp1 = (int)P + 1;
    #pragma unroll 4
    for (int j=0; j<Pp1; ++j){
      float f = fmaf(Bc[j], sm, A[j]) + Dt[j];
      if (f > best){ best = f; bj = (u32)j; }   // first max, like jnp.argmax
    }
    u32 opt = bj + 1u;
    atomicAdd(&optHist[(size_t)c*(B+2) + opt], 1u);
    s1 = (double)sm;
    s2 = (double)sm * (double)opt;
  }
  int tid = threadIdx.x;
  r1[tid]=s1; r2[tid]=s2; __syncthreads();
  for (int off=128; off>0; off>>=1){
    if (tid<off){ r1[tid]+=r1[tid+off]; r2[tid]+=r2[tid+off]; }
    __syncthreads();
  }
  if (tid==0){
    double* p = partials + ((size_t)c*gridDim.x + blockIdx.x)*2;
    p[0]=r1[0]; p[1]=r2[0];
  }
}

// Per-class finish: prefix-sum opt histogram -> r_plus, Delta, dot products, loss.
__global__ void k_finish(const float* __restrict__ sPos, const u32* __restrict__ Pcnt,
                         const u32* __restrict__ optHist, const float* __restrict__ Dtab,
                         const double* __restrict__ Cconst, const double* __restrict__ partials,
                         int B, int nblkM, double* __restrict__ classLoss){
  __shared__ u32 sc[1024];
  __shared__ double rd[1024];
  int c = blockIdx.x, tid = threadIdx.x;
  u32 P = Pcnt[c]; u32 N = (u32)B - P;
  if (P==0 || N==0){ if (tid==0) classLoss[c]=0.0; return; }
  const u32* hist = optHist + (size_t)c*(B+2);
  const float* sp = sPos + (size_t)c*B;
  double sumD=0.0, sumSpr=0.0, sumSp=0.0;
  u32 carry=0u;
  int nch = ((int)P + 1023)/1024;
  for (int ch=0; ch<nch; ++ch){
    int x = ch*1024 + tid;
    u32 v = (x < (int)P) ? hist[x+1] : 0u;
    sc[tid]=v; __syncthreads();
    for (int off=1; off<1024; off<<=1){
      u32 t2 = (tid>=off) ? sc[tid-off] : 0u;
      __syncthreads();
      sc[tid] += t2;
      __syncthreads();
    }
    u32 cum = sc[tid] + carry;   // inclusive prefix over hist[1..x+1]
    if (x < (int)P){
      u32 r = 1u + cum;          // r_plus[x]
      float spv = sp[x];
      sumD   += (double)Dtab[x + r];
      sumSpr += (double)spv * (double)r;
      sumSp  += (double)spv;
    }
    carry += sc[1023];
    __syncthreads();
  }
  rd[tid]=sumD; __syncthreads();
  for (int off=512; off>0; off>>=1){ if (tid<off) rd[tid]+=rd[tid+off]; __syncthreads(); }
  double totD = rd[0]; __syncthreads();
  rd[tid]=sumSpr; __syncthreads();
  for (int off=512; off>0; off>>=1){ if (tid<off) rd[tid]+=rd[tid+off]; __syncthreads(); }
  double totSpr = rd[0]; __syncthreads();
  rd[tid]=sumSp; __syncthreads();
  for (int off=512; off>0; off>>=1){ if (tid<off) rd[tid]+=rd[tid+off]; __syncthreads(); }
  double totSp = rd[0];
  if (tid==0){
    double S1=0.0, S2=0.0;
    const double* pp = partials + (size_t)c*nblkM*2;
    for (int b=0;b<nblkM;b++){ S1+=pp[2*b]; S2+=pp[2*b+1]; }
    double Cc = Cconst[c];
    double Delta = 1.0 - totD/Cc;
    double Fp    = (double)(N+2u)*totSp - 2.0*totSpr;   // sum s_plus*c_plus
    double Fm    = (double)(P+2u)*S1   - 2.0*S2;        // sum s_minus*c_minus
    double Fstar = (double)N*totSp - (double)P*S1;
    classLoss[c] = Delta + (Fp + Fm - Fstar)/((double)P*(double)N);
  }
}

__global__ void k_final(const double* __restrict__ classLoss, int NC, float* __restrict__ out){
  double s=0.0;
  for (int c=0;c<NC;c++) s += classLoss[c];
  out[0] = (float)(s/(double)NC);
}

extern "C" void kernel_launch(void* const* d_in, const int* in_sizes, int n_in,
                              void* d_out, int out_size, void* d_ws, size_t ws_size,
                              hipStream_t stream) {
  const float* scores = (const float*)d_in[0];
  const int*   labels = (const int*)d_in[1];
  int B  = in_sizes[1];
  int NC = in_sizes[0] / in_sizes[1];
  float* out = (float*)d_out;

  char* ws = (char*)d_ws;
  size_t off = 0;
  auto alloc = [&](size_t bytes)->char* {
    char* p = ws + off;
    off = (off + bytes + 255) & ~(size_t)255;
    return p;
  };
  float* Dtab    = (float*)alloc((size_t)(B+2)*4);
  // ---- zeroed region (bhist, Pcnt, optHist must be contiguous) ----
  char* zbeg = ws + off;
  u32* bhist   = (u32*)alloc((size_t)NC*2*NBUCKET*4);
  u32* Pcnt    = (u32*)alloc((size_t)NC*4);
  u32* optHist = (u32*)alloc((size_t)NC*(B+2)*4);
  char* zend = ws + off;
  // ----------------------------------------------------------------
  u32* bstart    = (u32*)alloc((size_t)NC*2*(NBUCKET+1)*4);
  u32* bcursor   = (u32*)alloc((size_t)NC*2*NBUCKET*4);
  u64* keyArr    = (u64*)alloc((size_t)NC*2*B*8);
  float* sPos    = (float*)alloc((size_t)NC*B*4);
  float* sNeg    = (float*)alloc((size_t)NC*B*4);
  float* Aarr    = (float*)alloc((size_t)NC*(B+1)*4);
  float* Barr    = (float*)alloc((size_t)NC*(B+1)*4);
  double* Cconst = (double*)alloc((size_t)NC*8);
  int nblkM = (B + 255)/256;
  double* partials  = (double*)alloc((size_t)NC*nblkM*2*8);
  double* classLoss = (double*)alloc((size_t)NC*8);

  hipMemsetAsync(zbeg, 0, (size_t)(zend - zbeg), stream);

  k_dtab<<<(B+2+255)/256, 256, 0, stream>>>(Dtab, B+2);
  k_hist<<<(B*NC+255)/256, 256, 0, stream>>>(scores, labels, B, NC, bhist, Pcnt);
  k_scan<<<NC*2, 1024, 0, stream>>>(bhist, bstart, bcursor);
  k_scatter<<<(B*NC+255)/256, 256, 0, stream>>>(scores, labels, B, NC, bcursor, keyArr);
  k_rank<<<dim3((B+255)/256, NC*2), 256, 0, stream>>>(keyArr, bstart, Pcnt, B, sPos, sNeg);
  k_pre<<<NC, 1024, 0, stream>>>(sPos, Pcnt, Dtab, B, Aarr, Barr, Cconst);
  k_main<<<dim3(nblkM, NC), 256, 0, stream>>>(sNeg, Pcnt, Dtab, Aarr, Barr, B, optHist, partials);
  k_finish<<<NC, 1024, 0, stream>>>(sPos, Pcnt, optHist, Dtab, Cconst, partials, B, nblkM, classLoss);
  k_final<<<1, 1, 0, stream>>>(classLoss, NC, out);
}

// Round 2
// 312.071 us; speedup vs baseline: 1.4353x; 1.4353x over previous
//
#include <hip/hip_runtime.h>
#include <stdint.h>
#include <math.h>

typedef unsigned int u32;
typedef unsigned long long u64;

#define NBUCKET 4096

__device__ __forceinline__ u32 f2key(float f){
  u32 b = __float_as_uint(f);
  return (b & 0x80000000u) ? ~b : (b | 0x80000000u);
}

// D table: Dtab[x] = 1/log2(1+x), x in [1, B+1]; Dtab[0] unused.
__global__ void k_dtab(float* __restrict__ Dtab, int n){
  int x = blockIdx.x*256 + threadIdx.x;
  if (x < n) Dtab[x] = (x==0) ? 0.0f : (float)(1.0/log2(1.0 + (double)x));
}

// Bucket histogram + P counts
__global__ void k_hist(const float* __restrict__ scores, const int* __restrict__ labels,
                       int B, int NC, u32* __restrict__ bhist, u32* __restrict__ Pcnt){
  int t = blockIdx.x*256 + threadIdx.x;
  if (t >= B*NC) return;
  int b = t / NC, c = t % NC;
  float v = scores[t];
  int isPos = (labels[b] == c);
  u32 u = f2key(v);
  u32 bucket = u >> 20;
  int pi = c*2 + (isPos ? 0 : 1);   // part0=pos, part1=neg
  atomicAdd(&bhist[(size_t)pi*NBUCKET + bucket], 1u);
  if (isPos) atomicAdd(&Pcnt[c], 1u);
}

// Exclusive scan of 4096 bins per (class,part); also init cursors.
__global__ void k_scan(const u32* __restrict__ bhist, u32* __restrict__ bstart, u32* __restrict__ bcursor){
  __shared__ u32 sc[1024];
  int pi = blockIdx.x, tid = threadIdx.x;
  const u32* h = bhist + (size_t)pi*NBUCKET;
  u32 v0 = h[tid*4+0], v1 = h[tid*4+1], v2 = h[tid*4+2], v3 = h[tid*4+3];
  u32 tot = v0+v1+v2+v3;
  sc[tid] = tot; __syncthreads();
  for (int off=1; off<1024; off<<=1){
    u32 t2 = (tid>=off) ? sc[tid-off] : 0u;
    __syncthreads();
    sc[tid] += t2;
    __syncthreads();
  }
  u32 run = sc[tid] - tot;  // exclusive prefix for this thread's 4 bins
  u32* bs = bstart  + (size_t)pi*(NBUCKET+1);
  u32* bc = bcursor + (size_t)pi*NBUCKET;
  bs[tid*4+0]=run; bc[tid*4+0]=run; run+=v0;
  bs[tid*4+1]=run; bc[tid*4+1]=run; run+=v1;
  bs[tid*4+2]=run; bc[tid*4+2]=run; run+=v2;
  bs[tid*4+3]=run; bc[tid*4+3]=run; run+=v3;
  if (tid==1023) bs[NBUCKET]=run;
}

// Scatter packed keys (key<<32 | orig_index) into bucket-grouped order.
__global__ void k_scatter(const float* __restrict__ scores, const int* __restrict__ labels,
                          int B, int NC, u32* __restrict__ bcursor, u64* __restrict__ keyArr){
  int t = blockIdx.x*256 + threadIdx.x;
  if (t >= B*NC) return;
  int b = t / NC, c = t % NC;
  float v = scores[t];
  int isPos = (labels[b] == c);
  u32 u = f2key(v);
  u32 bucket = u >> 20;
  int pi = c*2 + (isPos ? 0 : 1);
  u32 slot = atomicAdd(&bcursor[(size_t)pi*NBUCKET + bucket], 1u);
  keyArr[(size_t)pi*B + slot] = ((u64)u << 32) | (u32)b;
}

// Exact rank within bucket (deterministic via unique packed keys) -> sorted arrays.
__global__ void k_rank(const u64* __restrict__ keyArr, const u32* __restrict__ bstart,
                       const u32* __restrict__ Pcnt, int B,
                       float* __restrict__ sPos, float* __restrict__ sNeg){
  int pi = blockIdx.y; int c = pi >> 1; int part = pi & 1;
  u32 P = Pcnt[c];
  u32 cnt = part ? ((u32)B - P) : P;
  u32 t = blockIdx.x*256 + threadIdx.x;
  if (t >= cnt) return;
  const u64* ka = keyArr + (size_t)pi*B;
  u64 K = ka[t];
  u32 bucket = (u32)(K >> 52);
  const u32* bs = bstart + (size_t)pi*(NBUCKET+1);
  u32 lo = bs[bucket], hi = bs[bucket+1];
  u32 r = lo;
  for (u32 x=lo; x<hi; ++x) r += (ka[x] < K) ? 1u : 0u;
  u32 u = (u32)(K >> 32);
  u32 bits = (u & 0x80000000u) ? (u & 0x7fffffffu) : ~u;
  float val = __uint_as_float(bits);
  if (part == 0) sPos[(size_t)c*B + (P-1u-r)] = val;   // descending
  else           sNeg[(size_t)c*B + r]        = val;   // ascending
}

// Per-class: Cconst, prefix-scan-based suffix sums Sl -> scaled coefficients A', B'.
// Sl[j] = totSp - exclusive_prefix[j]; block-wide Hillis-Steele scan in LDS.
__global__ void k_pre(const float* __restrict__ sPos, const u32* __restrict__ Pcnt,
                      const float* __restrict__ Dtab, int B,
                      float* __restrict__ Aarr, float* __restrict__ Barr,
                      double* __restrict__ Cconst){
  __shared__ double sd[1024];
  int c = blockIdx.x, tid = threadIdx.x;
  u32 P = Pcnt[c]; u32 N = (u32)B - P;
  if (P==0 || N==0){ if (tid==0) Cconst[c]=1.0; return; }

  // Cc = sum Dtab[1..P]
  double s=0.0;
  for (u32 i=1+tid; i<=P; i+=1024) s += (double)Dtab[i];
  sd[tid]=s; __syncthreads();
  for (int off=512; off>0; off>>=1){ if (tid<off) sd[tid]+=sd[tid+off]; __syncthreads(); }
  double Cc = sd[0];
  if (tid==0) Cconst[c]=Cc;
  __syncthreads();

  const float* sp = sPos + (size_t)c*B;

  // totSp = sum sp[0..P-1]
  double ts=0.0;
  for (u32 i=tid; i<P; i+=1024) ts += (double)sp[i];
  sd[tid]=ts; __syncthreads();
  for (int off=512; off>0; off>>=1){ if (tid<off) sd[tid]+=sd[tid+off]; __syncthreads(); }
  double totSp = sd[0];
  __syncthreads();

  double PN = (double)P*(double)N;
  double ca = -2.0*Cc/PN;
  double cb =  2.0*Cc/PN;
  float* A  = Aarr + (size_t)c*(B+1);
  float* Bc = Barr + (size_t)c*(B+1);

  // chunked exclusive prefix scan over sp
  double carry=0.0;
  int nch = ((int)P + 1023)/1024;
  for (int ch=0; ch<nch; ++ch){
    int x = ch*1024 + tid;
    double v = (x < (int)P) ? (double)sp[x] : 0.0;
    sd[tid]=v; __syncthreads();
    for (int off2=1; off2<1024; off2<<=1){
      double t2 = (tid>=off2) ? sd[tid-off2] : 0.0;
      __syncthreads();
      sd[tid]+=t2;
      __syncthreads();
    }
    if (x < (int)P){
      double excl = sd[tid] - v + carry;      // sum sp[0..x-1]
      double Sl = totSp - excl;               // sum_{k=x}^{P-1} sp[k]
      A[x]  = (float)(ca*Sl);
      Bc[x] = (float)(cb*(double)(P-(u32)x));
    }
    carry += sd[1023];
    __syncthreads();
  }
  if (tid==0){ A[P]=0.0f; Bc[P]=0.0f; }
}

// Main: per negative m, argmax over j of fma(B'[j],sm,A'[j]) + Dtab[m+1+j]
__global__ void k_main(const float* __restrict__ sNeg, const u32* __restrict__ Pcnt,
                       const float* __restrict__ Dtab, const float* __restrict__ Aarr,
                       const float* __restrict__ Barr, int B,
                       u32* __restrict__ optHist, double* __restrict__ partials){
  __shared__ double r1[256], r2[256];
  int c = blockIdx.y;
  u32 P = Pcnt[c]; u32 N = (u32)B - P;
  int m = blockIdx.x*256 + threadIdx.x;
  double s1=0.0, s2=0.0;
  if (P>0u && N>0u && m < (int)N){
    float sm = sNeg[(size_t)c*B + m];
    const float* A  = Aarr + (size_t)c*(B+1);
    const float* Bc = Barr + (size_t)c*(B+1);
    const float* Dt = Dtab + m + 1;
    float best = -3.402823466e38f; u32 bj = 0u;
    int Pp1 = (int)P + 1;
    #pragma unroll 4
    for (int j=0; j<Pp1; ++j){
      float f = fmaf(Bc[j], sm, A[j]) + Dt[j];
      if (f > best){ best = f; bj = (u32)j; }   // first max, like jnp.argmax
    }
    u32 opt = bj + 1u;
    atomicAdd(&optHist[(size_t)c*(B+2) + opt], 1u);
    s1 = (double)sm;
    s2 = (double)sm * (double)opt;
  }
  int tid = threadIdx.x;
  r1[tid]=s1; r2[tid]=s2; __syncthreads();
  for (int off=128; off>0; off>>=1){
    if (tid<off){ r1[tid]+=r1[tid+off]; r2[tid]+=r2[tid+off]; }
    __syncthreads();
  }
  if (tid==0){
    double* p = partials + ((size_t)c*gridDim.x + blockIdx.x)*2;
    p[0]=r1[0]; p[1]=r2[0];
  }
}

// Per-class finish: prefix-sum opt histogram -> r_plus, Delta, dot products, loss.
__global__ void k_finish(const float* __restrict__ sPos, const u32* __restrict__ Pcnt,
                         const u32* __restrict__ optHist, const float* __restrict__ Dtab,
                         const double* __restrict__ Cconst, const double* __restrict__ partials,
                         int B, int nblkM, double* __restrict__ classLoss){
  __shared__ u32 sc[1024];
  __shared__ double rd[1024];
  int c = blockIdx.x, tid = threadIdx.x;
  u32 P = Pcnt[c]; u32 N = (u32)B - P;
  if (P==0 || N==0){ if (tid==0) classLoss[c]=0.0; return; }
  const u32* hist = optHist + (size_t)c*(B+2);
  const float* sp = sPos + (size_t)c*B;
  double sumD=0.0, sumSpr=0.0, sumSp=0.0;
  u32 carry=0u;
  int nch = ((int)P + 1023)/1024;
  for (int ch=0; ch<nch; ++ch){
    int x = ch*1024 + tid;
    u32 v = (x < (int)P) ? hist[x+1] : 0u;
    sc[tid]=v; __syncthreads();
    for (int off=1; off<1024; off<<=1){
      u32 t2 = (tid>=off) ? sc[tid-off] : 0u;
      __syncthreads();
      sc[tid] += t2;
      __syncthreads();
    }
    u32 cum = sc[tid] + carry;   // inclusive prefix over hist[1..x+1]
    if (x < (int)P){
      u32 r = 1u + cum;          // r_plus[x]
      float spv = sp[x];
      sumD   += (double)Dtab[x + r];
      sumSpr += (double)spv * (double)r;
      sumSp  += (double)spv;
    }
    carry += sc[1023];
    __syncthreads();
  }
  rd[tid]=sumD; __syncthreads();
  for (int off=512; off>0; off>>=1){ if (tid<off) rd[tid]+=rd[tid+off]; __syncthreads(); }
  double totD = rd[0]; __syncthreads();
  rd[tid]=sumSpr; __syncthreads();
  for (int off=512; off>0; off>>=1){ if (tid<off) rd[tid]+=rd[tid+off]; __syncthreads(); }
  double totSpr = rd[0]; __syncthreads();
  rd[tid]=sumSp; __syncthreads();
  for (int off=512; off>0; off>>=1){ if (tid<off) rd[tid]+=rd[tid+off]; __syncthreads(); }
  double totSp = rd[0];
  if (tid==0){
    double S1=0.0, S2=0.0;
    const double* pp = partials + (size_t)c*nblkM*2;
    for (int b=0;b<nblkM;b++){ S1+=pp[2*b]; S2+=pp[2*b+1]; }
    double Cc = Cconst[c];
    double Delta = 1.0 - totD/Cc;
    double Fp    = (double)(N+2u)*totSp - 2.0*totSpr;   // sum s_plus*c_plus
    double Fm    = (double)(P+2u)*S1   - 2.0*S2;        // sum s_minus*c_minus
    double Fstar = (double)N*totSp - (double)P*S1;
    classLoss[c] = Delta + (Fp + Fm - Fstar)/((double)P*(double)N);
  }
}

__global__ void k_final(const double* __restrict__ classLoss, int NC, float* __restrict__ out){
  double s=0.0;
  for (int c=0;c<NC;c++) s += classLoss[c];
  out[0] = (float)(s/(double)NC);
}

extern "C" void kernel_launch(void* const* d_in, const int* in_sizes, int n_in,
                              void* d_out, int out_size, void* d_ws, size_t ws_size,
                              hipStream_t stream) {
  const float* scores = (const float*)d_in[0];
  const int*   labels = (const int*)d_in[1];
  int B  = in_sizes[1];
  int NC = in_sizes[0] / in_sizes[1];
  float* out = (float*)d_out;

  char* ws = (char*)d_ws;
  size_t off = 0;
  auto alloc = [&](size_t bytes)->char* {
    char* p = ws + off;
    off = (off + bytes + 255) & ~(size_t)255;
    return p;
  };
  float* Dtab    = (float*)alloc((size_t)(B+2)*4);
  // ---- zeroed region (bhist, Pcnt, optHist must be contiguous) ----
  char* zbeg = ws + off;
  u32* bhist   = (u32*)alloc((size_t)NC*2*NBUCKET*4);
  u32* Pcnt    = (u32*)alloc((size_t)NC*4);
  u32* optHist = (u32*)alloc((size_t)NC*(B+2)*4);
  char* zend = ws + off;
  // ----------------------------------------------------------------
  u32* bstart    = (u32*)alloc((size_t)NC*2*(NBUCKET+1)*4);
  u32* bcursor   = (u32*)alloc((size_t)NC*2*NBUCKET*4);
  u64* keyArr    = (u64*)alloc((size_t)NC*2*B*8);
  float* sPos    = (float*)alloc((size_t)NC*B*4);
  float* sNeg    = (float*)alloc((size_t)NC*B*4);
  float* Aarr    = (float*)alloc((size_t)NC*(B+1)*4);
  float* Barr    = (float*)alloc((size_t)NC*(B+1)*4);
  double* Cconst = (double*)alloc((size_t)NC*8);
  int nblkM = (B + 255)/256;
  double* partials  = (double*)alloc((size_t)NC*nblkM*2*8);
  double* classLoss = (double*)alloc((size_t)NC*8);

  hipMemsetAsync(zbeg, 0, (size_t)(zend - zbeg), stream);

  k_dtab<<<(B+2+255)/256, 256, 0, stream>>>(Dtab, B+2);
  k_hist<<<(B*NC+255)/256, 256, 0, stream>>>(scores, labels, B, NC, bhist, Pcnt);
  k_scan<<<NC*2, 1024, 0, stream>>>(bhist, bstart, bcursor);
  k_scatter<<<(B*NC+255)/256, 256, 0, stream>>>(scores, labels, B, NC, bcursor, keyArr);
  k_rank<<<dim3((B+255)/256, NC*2), 256, 0, stream>>>(keyArr, bstart, Pcnt, B, sPos, sNeg);
  k_pre<<<NC, 1024, 0, stream>>>(sPos, Pcnt, Dtab, B, Aarr, Barr, Cconst);
  k_main<<<dim3(nblkM, NC), 256, 0, stream>>>(sNeg, Pcnt, Dtab, Aarr, Barr, B, optHist, partials);
  k_finish<<<NC, 1024, 0, stream>>>(sPos, Pcnt, optHist, Dtab, Cconst, partials, B, nblkM, classLoss);
  k_final<<<1, 1, 0, stream>>>(classLoss, NC, out);
}

// Round 3
// 307.147 us; speedup vs baseline: 1.4583x; 1.0160x over previous
//
#include <hip/hip_runtime.h>
#include <stdint.h>
#include <math.h>

typedef unsigned int u32;
typedef unsigned long long u64;

#define NBUCKET 16384   // radix = top 14 bits of order-preserving key
#define BSHIFT  18      // u >> 18 -> 14-bit bucket

__device__ __forceinline__ u32 f2key(float f){
  u32 b = __float_as_uint(f);
  return (b & 0x80000000u) ? ~b : (b | 0x80000000u);
}

// D table: Dtab[x] = 1/log2(1+x), x in [1, B+1]; Dtab[0] unused.
__global__ void k_dtab(float* __restrict__ Dtab, int n){
  int x = blockIdx.x*256 + threadIdx.x;
  if (x < n) Dtab[x] = (x==0) ? 0.0f : (float)(1.0/log2(1.0 + (double)x));
}

// Bucket histogram + P counts
__global__ void k_hist(const float* __restrict__ scores, const int* __restrict__ labels,
                       int B, int NC, u32* __restrict__ bhist, u32* __restrict__ Pcnt){
  int t = blockIdx.x*256 + threadIdx.x;
  if (t >= B*NC) return;
  int b = t / NC, c = t % NC;
  float v = scores[t];
  int isPos = (labels[b] == c);
  u32 u = f2key(v);
  u32 bucket = u >> BSHIFT;
  int pi = c*2 + (isPos ? 0 : 1);   // part0=pos, part1=neg
  atomicAdd(&bhist[(size_t)pi*NBUCKET + bucket], 1u);
  if (isPos) atomicAdd(&Pcnt[c], 1u);
}

// Exclusive scan of 16384 bins per (class,part); 16 bins/thread; init cursors.
__global__ void k_scan(const u32* __restrict__ bhist, u32* __restrict__ bstart, u32* __restrict__ bcursor){
  __shared__ u32 sc[1024];
  int pi = blockIdx.x, tid = threadIdx.x;
  const u32* h = bhist + (size_t)pi*NBUCKET;
  u32 v[16]; u32 tot = 0u;
  #pragma unroll
  for (int k=0;k<16;k++){ v[k] = h[tid*16+k]; tot += v[k]; }
  sc[tid] = tot; __syncthreads();
  for (int off=1; off<1024; off<<=1){
    u32 t2 = (tid>=off) ? sc[tid-off] : 0u;
    __syncthreads();
    sc[tid] += t2;
    __syncthreads();
  }
  u32 run = sc[tid] - tot;  // exclusive prefix for this thread's 16 bins
  u32* bs = bstart  + (size_t)pi*(NBUCKET+1);
  u32* bc = bcursor + (size_t)pi*NBUCKET;
  #pragma unroll
  for (int k=0;k<16;k++){ bs[tid*16+k]=run; bc[tid*16+k]=run; run+=v[k]; }
  if (tid==1023) bs[NBUCKET]=run;
}

// Scatter packed keys (key<<32 | orig_index) into bucket-grouped order.
__global__ void k_scatter(const float* __restrict__ scores, const int* __restrict__ labels,
                          int B, int NC, u32* __restrict__ bcursor, u64* __restrict__ keyArr){
  int t = blockIdx.x*256 + threadIdx.x;
  if (t >= B*NC) return;
  int b = t / NC, c = t % NC;
  float v = scores[t];
  int isPos = (labels[b] == c);
  u32 u = f2key(v);
  u32 bucket = u >> BSHIFT;
  int pi = c*2 + (isPos ? 0 : 1);
  u32 slot = atomicAdd(&bcursor[(size_t)pi*NBUCKET + bucket], 1u);
  keyArr[(size_t)pi*B + slot] = ((u64)u << 32) | (u32)b;
}

// Exact rank within bucket (deterministic via unique packed keys) -> sorted arrays.
__global__ void k_rank(const u64* __restrict__ keyArr, const u32* __restrict__ bstart,
                       const u32* __restrict__ Pcnt, int B,
                       float* __restrict__ sPos, float* __restrict__ sNeg){
  int pi = blockIdx.y; int c = pi >> 1; int part = pi & 1;
  u32 P = Pcnt[c];
  u32 cnt = part ? ((u32)B - P) : P;
  u32 t = blockIdx.x*256 + threadIdx.x;
  if (t >= cnt) return;
  const u64* ka = keyArr + (size_t)pi*B;
  u64 K = ka[t];
  u32 bucket = (u32)(K >> (32 + BSHIFT));
  const u32* bs = bstart + (size_t)pi*(NBUCKET+1);
  u32 lo = bs[bucket], hi = bs[bucket+1];
  u32 r = lo;
  for (u32 x=lo; x<hi; ++x) r += (ka[x] < K) ? 1u : 0u;
  u32 u = (u32)(K >> 32);
  u32 bits = (u & 0x80000000u) ? (u & 0x7fffffffu) : ~u;
  float val = __uint_as_float(bits);
  if (part == 0) sPos[(size_t)c*B + (P-1u-r)] = val;   // descending
  else           sNeg[(size_t)c*B + r]        = val;   // ascending
}

// Per-class: Cconst, prefix-scan-based suffix sums Sl -> scaled coefficients A', B'.
__global__ void k_pre(const float* __restrict__ sPos, const u32* __restrict__ Pcnt,
                      const float* __restrict__ Dtab, int B,
                      float* __restrict__ Aarr, float* __restrict__ Barr,
                      double* __restrict__ Cconst){
  __shared__ double sd[1024];
  int c = blockIdx.x, tid = threadIdx.x;
  u32 P = Pcnt[c]; u32 N = (u32)B - P;
  if (P==0 || N==0){ if (tid==0) Cconst[c]=1.0; return; }

  double s=0.0;
  for (u32 i=1+tid; i<=P; i+=1024) s += (double)Dtab[i];
  sd[tid]=s; __syncthreads();
  for (int off=512; off>0; off>>=1){ if (tid<off) sd[tid]+=sd[tid+off]; __syncthreads(); }
  double Cc = sd[0];
  if (tid==0) Cconst[c]=Cc;
  __syncthreads();

  const float* sp = sPos + (size_t)c*B;

  double ts=0.0;
  for (u32 i=tid; i<P; i+=1024) ts += (double)sp[i];
  sd[tid]=ts; __syncthreads();
  for (int off=512; off>0; off>>=1){ if (tid<off) sd[tid]+=sd[tid+off]; __syncthreads(); }
  double totSp = sd[0];
  __syncthreads();

  double PN = (double)P*(double)N;
  double ca = -2.0*Cc/PN;
  double cb =  2.0*Cc/PN;
  float* A  = Aarr + (size_t)c*(B+1);
  float* Bc = Barr + (size_t)c*(B+1);

  double carry=0.0;
  int nch = ((int)P + 1023)/1024;
  for (int ch=0; ch<nch; ++ch){
    int x = ch*1024 + tid;
    double v = (x < (int)P) ? (double)sp[x] : 0.0;
    sd[tid]=v; __syncthreads();
    for (int off2=1; off2<1024; off2<<=1){
      double t2 = (tid>=off2) ? sd[tid-off2] : 0.0;
      __syncthreads();
      sd[tid]+=t2;
      __syncthreads();
    }
    if (x < (int)P){
      double excl = sd[tid] - v + carry;      // sum sp[0..x-1]
      double Sl = totSp - excl;               // sum_{k=x}^{P-1} sp[k]
      A[x]  = (float)(ca*Sl);
      Bc[x] = (float)(cb*(double)(P-(u32)x));
    }
    carry += sd[1023];
    __syncthreads();
  }
  if (tid==0){ A[P]=0.0f; Bc[P]=0.0f; }
}

// Main: per negative m, argmax over j of fma(B'[j],sm,A'[j]) + Dtab[m+1+j].
// Block = 64 m-lanes x 4 j-chunks; chunk partials combined via packed u64 key
// whose max == first-max argmax (tie -> smaller j wins via ~bj).
#define JCHUNKS 4
__global__ void k_main(const float* __restrict__ sNeg, const u32* __restrict__ Pcnt,
                       const float* __restrict__ Dtab, const float* __restrict__ Aarr,
                       const float* __restrict__ Barr, int B,
                       u32* __restrict__ optHist, double* __restrict__ partials){
  __shared__ u64 skey[256];
  int c = blockIdx.y;
  u32 P = Pcnt[c]; u32 N = (u32)B - P;
  int tm = threadIdx.x & 63;
  int tj = threadIdx.x >> 6;
  int m  = blockIdx.x*64 + tm;

  float sm = 0.0f;
  u64 key = 0ull;
  bool valid = (P>0u && N>0u && m < (int)N);
  if (valid){
    sm = sNeg[(size_t)c*B + m];
    const float* A  = Aarr + (size_t)c*(B+1);
    const float* Bc = Barr + (size_t)c*(B+1);
    const float* Dt = Dtab + m + 1;
    int total = (int)P + 1;
    int CH = (total + JCHUNKS - 1)/JCHUNKS;
    int j0 = tj*CH;
    int j1 = min(j0+CH, total);
    float best = -3.402823466e38f; u32 bj = 0xFFFFFFFFu;
    #pragma unroll 4
    for (int j=j0; j<j1; ++j){
      float f = fmaf(Bc[j], sm, A[j]) + Dt[j];
      if (f > best){ best = f; bj = (u32)j; }   // first max within chunk
    }
    if (bj != 0xFFFFFFFFu)
      key = ((u64)f2key(best + 0.0f) << 32) | (u32)(~bj);  // +0.0f canonicalizes -0
  }
  skey[threadIdx.x] = key;
  __syncthreads();

  if (tj == 0){   // threads 0..63 = wave 0
    u64 k0 = skey[tm], k1 = skey[64+tm], k2 = skey[128+tm], k3 = skey[192+tm];
    u64 kk = max(max(k0,k1), max(k2,k3));
    double s1 = 0.0, s2 = 0.0;
    if (valid){
      u32 bj = ~(u32)kk;          // absolute best j
      u32 opt = bj + 1u;
      atomicAdd(&optHist[(size_t)c*(B+2) + opt], 1u);
      s1 = (double)sm;
      s2 = (double)sm * (double)opt;
    }
    // wave-64 shuffle reduction (single wave, no barriers needed)
    for (int off=32; off>0; off>>=1){
      s1 += __shfl_down(s1, off);
      s2 += __shfl_down(s2, off);
    }
    if (tm == 0){
      double* p = partials + ((size_t)c*gridDim.x + blockIdx.x)*2;
      p[0]=s1; p[1]=s2;
    }
  }
}

// Per-class finish: prefix-sum opt histogram -> r_plus, Delta, dot products, loss.
__global__ void k_finish(const float* __restrict__ sPos, const u32* __restrict__ Pcnt,
                         const u32* __restrict__ optHist, const float* __restrict__ Dtab,
                         const double* __restrict__ Cconst, const double* __restrict__ partials,
                         int B, int nblkM, double* __restrict__ classLoss){
  __shared__ u32 sc[1024];
  __shared__ double rd[1024];
  int c = blockIdx.x, tid = threadIdx.x;
  u32 P = Pcnt[c]; u32 N = (u32)B - P;
  if (P==0 || N==0){ if (tid==0) classLoss[c]=0.0; return; }
  const u32* hist = optHist + (size_t)c*(B+2);
  const float* sp = sPos + (size_t)c*B;
  double sumD=0.0, sumSpr=0.0, sumSp=0.0;
  u32 carry=0u;
  int nch = ((int)P + 1023)/1024;
  for (int ch=0; ch<nch; ++ch){
    int x = ch*1024 + tid;
    u32 v = (x < (int)P) ? hist[x+1] : 0u;
    sc[tid]=v; __syncthreads();
    for (int off=1; off<1024; off<<=1){
      u32 t2 = (tid>=off) ? sc[tid-off] : 0u;
      __syncthreads();
      sc[tid] += t2;
      __syncthreads();
    }
    u32 cum = sc[tid] + carry;   // inclusive prefix over hist[1..x+1]
    if (x < (int)P){
      u32 r = 1u + cum;          // r_plus[x]
      float spv = sp[x];
      sumD   += (double)Dtab[x + r];
      sumSpr += (double)spv * (double)r;
      sumSp  += (double)spv;
    }
    carry += sc[1023];
    __syncthreads();
  }
  rd[tid]=sumD; __syncthreads();
  for (int off=512; off>0; off>>=1){ if (tid<off) rd[tid]+=rd[tid+off]; __syncthreads(); }
  double totD = rd[0]; __syncthreads();
  rd[tid]=sumSpr; __syncthreads();
  for (int off=512; off>0; off>>=1){ if (tid<off) rd[tid]+=rd[tid+off]; __syncthreads(); }
  double totSpr = rd[0]; __syncthreads();
  rd[tid]=sumSp; __syncthreads();
  for (int off=512; off>0; off>>=1){ if (tid<off) rd[tid]+=rd[tid+off]; __syncthreads(); }
  double totSp = rd[0];
  if (tid==0){
    double S1=0.0, S2=0.0;
    const double* pp = partials + (size_t)c*nblkM*2;
    for (int b=0;b<nblkM;b++){ S1+=pp[2*b]; S2+=pp[2*b+1]; }
    double Cc = Cconst[c];
    double Delta = 1.0 - totD/Cc;
    double Fp    = (double)(N+2u)*totSp - 2.0*totSpr;   // sum s_plus*c_plus
    double Fm    = (double)(P+2u)*S1   - 2.0*S2;        // sum s_minus*c_minus
    double Fstar = (double)N*totSp - (double)P*S1;
    classLoss[c] = Delta + (Fp + Fm - Fstar)/((double)P*(double)N);
  }
}

__global__ void k_final(const double* __restrict__ classLoss, int NC, float* __restrict__ out){
  double s=0.0;
  for (int c=0;c<NC;c++) s += classLoss[c];
  out[0] = (float)(s/(double)NC);
}

extern "C" void kernel_launch(void* const* d_in, const int* in_sizes, int n_in,
                              void* d_out, int out_size, void* d_ws, size_t ws_size,
                              hipStream_t stream) {
  const float* scores = (const float*)d_in[0];
  const int*   labels = (const int*)d_in[1];
  int B  = in_sizes[1];
  int NC = in_sizes[0] / in_sizes[1];
  float* out = (float*)d_out;

  char* ws = (char*)d_ws;
  size_t off = 0;
  auto alloc = [&](size_t bytes)->char* {
    char* p = ws + off;
    off = (off + bytes + 255) & ~(size_t)255;
    return p;
  };
  float* Dtab    = (float*)alloc((size_t)(B+2)*4);
  // ---- zeroed region (bhist, Pcnt, optHist must be contiguous) ----
  char* zbeg = ws + off;
  u32* bhist   = (u32*)alloc((size_t)NC*2*NBUCKET*4);
  u32* Pcnt    = (u32*)alloc((size_t)NC*4);
  u32* optHist = (u32*)alloc((size_t)NC*(B+2)*4);
  char* zend = ws + off;
  // ----------------------------------------------------------------
  u32* bstart    = (u32*)alloc((size_t)NC*2*(NBUCKET+1)*4);
  u32* bcursor   = (u32*)alloc((size_t)NC*2*NBUCKET*4);
  u64* keyArr    = (u64*)alloc((size_t)NC*2*B*8);
  float* sPos    = (float*)alloc((size_t)NC*B*4);
  float* sNeg    = (float*)alloc((size_t)NC*B*4);
  float* Aarr    = (float*)alloc((size_t)NC*(B+1)*4);
  float* Barr    = (float*)alloc((size_t)NC*(B+1)*4);
  double* Cconst = (double*)alloc((size_t)NC*8);
  int nblkM = (B + 63)/64;
  double* partials  = (double*)alloc((size_t)NC*nblkM*2*8);
  double* classLoss = (double*)alloc((size_t)NC*8);

  hipMemsetAsync(zbeg, 0, (size_t)(zend - zbeg), stream);

  k_dtab<<<(B+2+255)/256, 256, 0, stream>>>(Dtab, B+2);
  k_hist<<<(B*NC+255)/256, 256, 0, stream>>>(scores, labels, B, NC, bhist, Pcnt);
  k_scan<<<NC*2, 1024, 0, stream>>>(bhist, bstart, bcursor);
  k_scatter<<<(B*NC+255)/256, 256, 0, stream>>>(scores, labels, B, NC, bcursor, keyArr);
  k_rank<<<dim3((B+255)/256, NC*2), 256, 0, stream>>>(keyArr, bstart, Pcnt, B, sPos, sNeg);
  k_pre<<<NC, 1024, 0, stream>>>(sPos, Pcnt, Dtab, B, Aarr, Barr, Cconst);
  k_main<<<dim3(nblkM, NC), 256, 0, stream>>>(sNeg, Pcnt, Dtab, Aarr, Barr, B, optHist, partials);
  k_finish<<<NC, 1024, 0, stream>>>(sPos, Pcnt, optHist, Dtab, Cconst, partials, B, nblkM, classLoss);
  k_final<<<1, 1, 0, stream>>>(classLoss, NC, out);
}

// Round 4
// 255.468 us; speedup vs baseline: 1.7533x; 1.2023x over previous
//
#include <hip/hip_runtime.h>
#include <stdint.h>
#include <math.h>

typedef unsigned int u32;
typedef unsigned long long u64;

#define NBUCKET 16384   // radix = top 14 bits of order-preserving key
#define BSHIFT  18      // u >> 18 -> 14-bit bucket

__device__ __forceinline__ u32 f2key(float f){
  u32 b = __float_as_uint(f);
  return (b & 0x80000000u) ? ~b : (b | 0x80000000u);
}

// Fused: bucket histogram + P counts + D-table fill (4 phase-shifted copies).
// Dsh[p*SD + y] = D(y+p) = 1/log2(1+(y+p)); slot (p=0,y=0) unused -> 0.
__global__ void k_hist(const float* __restrict__ scores, const int* __restrict__ labels,
                       int B, int NC, u32* __restrict__ bhist, u32* __restrict__ Pcnt,
                       float* __restrict__ Dsh, int SD){
  int t = blockIdx.x*256 + threadIdx.x;
  if (t < 4*SD){
    int p = t / SD, y = t - p*SD;
    long long x = (long long)y + p;
    Dsh[t] = (x==0) ? 0.0f : (float)(1.0/log2(1.0 + (double)x));
  }
  if (t >= B*NC) return;
  int b = t / NC, c = t - (t/NC)*NC;
  float v = scores[t];
  int isPos = (labels[b] == c);
  u32 u = f2key(v);
  u32 bucket = u >> BSHIFT;
  int pi = c*2 + (isPos ? 0 : 1);   // part0=pos, part1=neg
  atomicAdd(&bhist[(size_t)pi*NBUCKET + bucket], 1u);
  if (isPos) atomicAdd(&Pcnt[c], 1u);
}

// Exclusive scan of 16384 bins per (class,part); 16 bins/thread; init cursors.
__global__ void k_scan(const u32* __restrict__ bhist, u32* __restrict__ bstart, u32* __restrict__ bcursor){
  __shared__ u32 sc[1024];
  int pi = blockIdx.x, tid = threadIdx.x;
  const u32* h = bhist + (size_t)pi*NBUCKET;
  u32 v[16]; u32 tot = 0u;
  #pragma unroll
  for (int k=0;k<16;k++){ v[k] = h[tid*16+k]; tot += v[k]; }
  sc[tid] = tot; __syncthreads();
  for (int off=1; off<1024; off<<=1){
    u32 t2 = (tid>=off) ? sc[tid-off] : 0u;
    __syncthreads();
    sc[tid] += t2;
    __syncthreads();
  }
  u32 run = sc[tid] - tot;  // exclusive prefix for this thread's 16 bins
  u32* bs = bstart  + (size_t)pi*(NBUCKET+1);
  u32* bc = bcursor + (size_t)pi*NBUCKET;
  #pragma unroll
  for (int k=0;k<16;k++){ bs[tid*16+k]=run; bc[tid*16+k]=run; run+=v[k]; }
  if (tid==1023) bs[NBUCKET]=run;
}

// Scatter packed keys (key<<32 | orig_index) into bucket-grouped order.
__global__ void k_scatter(const float* __restrict__ scores, const int* __restrict__ labels,
                          int B, int NC, u32* __restrict__ bcursor, u64* __restrict__ keyArr){
  int t = blockIdx.x*256 + threadIdx.x;
  if (t >= B*NC) return;
  int b = t / NC, c = t - (t/NC)*NC;
  float v = scores[t];
  int isPos = (labels[b] == c);
  u32 u = f2key(v);
  u32 bucket = u >> BSHIFT;
  int pi = c*2 + (isPos ? 0 : 1);
  u32 slot = atomicAdd(&bcursor[(size_t)pi*NBUCKET + bucket], 1u);
  keyArr[(size_t)pi*B + slot] = ((u64)u << 32) | (u32)b;
}

// Exact rank within bucket (deterministic via unique packed keys) -> sorted arrays.
__global__ void k_rank(const u64* __restrict__ keyArr, const u32* __restrict__ bstart,
                       const u32* __restrict__ Pcnt, int B,
                       float* __restrict__ sPos, float* __restrict__ sNeg){
  int pi = blockIdx.y; int c = pi >> 1; int part = pi & 1;
  u32 P = Pcnt[c];
  u32 cnt = part ? ((u32)B - P) : P;
  u32 t = blockIdx.x*256 + threadIdx.x;
  if (t >= cnt) return;
  const u64* ka = keyArr + (size_t)pi*B;
  u64 K = ka[t];
  u32 bucket = (u32)(K >> (32 + BSHIFT));
  const u32* bs = bstart + (size_t)pi*(NBUCKET+1);
  u32 lo = bs[bucket], hi = bs[bucket+1];
  u32 r = lo;
  for (u32 x=lo; x<hi; ++x) r += (ka[x] < K) ? 1u : 0u;
  u32 u = (u32)(K >> 32);
  u32 bits = (u & 0x80000000u) ? (u & 0x7fffffffu) : ~u;
  float val = __uint_as_float(bits);
  if (part == 0) sPos[(size_t)c*B + (P-1u-r)] = val;   // descending
  else           sNeg[(size_t)c*B + r]        = val;   // ascending
}

// Per-class: Cconst, prefix-scan-based suffix sums Sl -> scaled coefficients A', B'.
__global__ void k_pre(const float* __restrict__ sPos, const u32* __restrict__ Pcnt,
                      const float* __restrict__ Dsh, int B, int strideAB,
                      float* __restrict__ Aarr, float* __restrict__ Barr,
                      double* __restrict__ Cconst){
  __shared__ double sd[1024];
  int c = blockIdx.x, tid = threadIdx.x;
  u32 P = Pcnt[c]; u32 N = (u32)B - P;
  if (P==0 || N==0){ if (tid==0) Cconst[c]=1.0; return; }

  double s=0.0;
  for (u32 i=1+tid; i<=P; i+=1024) s += (double)Dsh[i];   // copy 0 == plain Dtab
  sd[tid]=s; __syncthreads();
  for (int off=512; off>0; off>>=1){ if (tid<off) sd[tid]+=sd[tid+off]; __syncthreads(); }
  double Cc = sd[0];
  if (tid==0) Cconst[c]=Cc;
  __syncthreads();

  const float* sp = sPos + (size_t)c*B;

  double ts=0.0;
  for (u32 i=tid; i<P; i+=1024) ts += (double)sp[i];
  sd[tid]=ts; __syncthreads();
  for (int off=512; off>0; off>>=1){ if (tid<off) sd[tid]+=sd[tid+off]; __syncthreads(); }
  double totSp = sd[0];
  __syncthreads();

  double PN = (double)P*(double)N;
  double ca = -2.0*Cc/PN;
  double cb =  2.0*Cc/PN;
  float* A  = Aarr + (size_t)c*strideAB;
  float* Bc = Barr + (size_t)c*strideAB;

  double carry=0.0;
  int nch = ((int)P + 1023)/1024;
  for (int ch=0; ch<nch; ++ch){
    int x = ch*1024 + tid;
    double v = (x < (int)P) ? (double)sp[x] : 0.0;
    sd[tid]=v; __syncthreads();
    for (int off2=1; off2<1024; off2<<=1){
      double t2 = (tid>=off2) ? sd[tid-off2] : 0.0;
      __syncthreads();
      sd[tid]+=t2;
      __syncthreads();
    }
    if (x < (int)P){
      double excl = sd[tid] - v + carry;      // sum sp[0..x-1]
      double Sl = totSp - excl;               // sum_{k=x}^{P-1} sp[k]
      A[x]  = (float)(ca*Sl);
      Bc[x] = (float)(cb*(double)(P-(u32)x));
    }
    carry += sd[1023];
    __syncthreads();
  }
  if (tid==0){ A[P]=0.0f; Bc[P]=0.0f; }
}

// Main: lane handles m = blk*256 + wave + 4*lane (stride-4 so Dt windows are
// 16B-aligned via phase-shifted Dtab copies). Per 4 j's: 1 float4 Dt load
// (coalesced) + 2 uniform float4 A/B loads + 4x{fma,add,cmp,2 sel}.
__global__ void k_main(const float* __restrict__ sNeg, const u32* __restrict__ Pcnt,
                       const float* __restrict__ Dsh, int SD,
                       const float* __restrict__ Aarr, const float* __restrict__ Barr,
                       int B, int strideAB,
                       u32* __restrict__ optHist, double* __restrict__ partials){
  __shared__ double l1[4], l2[4];
  int c = blockIdx.y;
  u32 P = Pcnt[c]; u32 N = (u32)B - P;
  int w    = threadIdx.x >> 6;
  int lane = threadIdx.x & 63;
  int m = blockIdx.x*256 + w + 4*lane;
  double s1=0.0, s2=0.0;
  bool valid = (P>0u && N>0u && m < (int)N);
  if (valid){
    float sm = sNeg[(size_t)c*B + m];
    const float* A  = Aarr + (size_t)c*strideAB;
    const float* Bc = Barr + (size_t)c*strideAB;
    int ph = (m+1) & 3;                              // wave-uniform (m stride 4)
    const float* Dp = Dsh + (size_t)ph*SD + (m+1-ph); // Dp[j]=D(m+1+j); 16B-aligned at j%4==0
    int total = (int)P + 1;
    int jmax4 = total & ~3;
    float best = -3.402823466e38f; u32 bj = 0u;
    int j = 0;
    #pragma unroll 2
    for (; j < jmax4; j += 4){
      float4 d = *(const float4*)(Dp + j);
      float4 a = *(const float4*)(A + j);
      float4 b = *(const float4*)(Bc + j);
      float f0 = fmaf(b.x, sm, a.x) + d.x;
      float f1 = fmaf(b.y, sm, a.y) + d.y;
      float f2 = fmaf(b.z, sm, a.z) + d.z;
      float f3 = fmaf(b.w, sm, a.w) + d.w;
      if (f0 > best){ best=f0; bj=(u32)j; }
      if (f1 > best){ best=f1; bj=(u32)(j+1); }
      if (f2 > best){ best=f2; bj=(u32)(j+2); }
      if (f3 > best){ best=f3; bj=(u32)(j+3); }
    }
    for (; j < total; ++j){
      float f = fmaf(Bc[j], sm, A[j]) + Dp[j];
      if (f > best){ best=f; bj=(u32)j; }
    }
    u32 opt = bj + 1u;
    atomicAdd(&optHist[(size_t)c*(B+2) + opt], 1u);
    s1 = (double)sm;
    s2 = (double)sm * (double)opt;
  }
  for (int off=32; off>0; off>>=1){
    s1 += __shfl_down(s1, off);
    s2 += __shfl_down(s2, off);
  }
  if (lane==0){ l1[w]=s1; l2[w]=s2; }
  __syncthreads();
  if (threadIdx.x==0){
    double* p = partials + ((size_t)c*gridDim.x + blockIdx.x)*2;
    p[0] = l1[0]+l1[1]+l1[2]+l1[3];
    p[1] = l2[0]+l2[1]+l2[2]+l2[3];
  }
}

// Per-class finish: prefix-sum opt histogram -> r_plus, Delta, dots, class loss.
// Fused finalization: last block to finish sums classLoss and writes out[0].
__global__ void k_finish(const float* __restrict__ sPos, const u32* __restrict__ Pcnt,
                         const u32* __restrict__ optHist, const float* __restrict__ Dsh,
                         const double* __restrict__ Cconst, const double* __restrict__ partials,
                         int B, int nblkM, int NC,
                         u64* __restrict__ classLoss, u32* __restrict__ doneCount,
                         float* __restrict__ out){
  __shared__ u32 sc[1024];
  __shared__ double rd[1024];
  int c = blockIdx.x, tid = threadIdx.x;
  u32 P = Pcnt[c]; u32 N = (u32)B - P;
  double myLoss = 0.0;
  if (P!=0 && N!=0){
    const u32* hist = optHist + (size_t)c*(B+2);
    const float* sp = sPos + (size_t)c*B;
    double sumD=0.0, sumSpr=0.0, sumSp=0.0;
    u32 carry=0u;
    int nch = ((int)P + 1023)/1024;
    for (int ch=0; ch<nch; ++ch){
      int x = ch*1024 + tid;
      u32 v = (x < (int)P) ? hist[x+1] : 0u;
      sc[tid]=v; __syncthreads();
      for (int off=1; off<1024; off<<=1){
        u32 t2 = (tid>=off) ? sc[tid-off] : 0u;
        __syncthreads();
        sc[tid] += t2;
        __syncthreads();
      }
      u32 cum = sc[tid] + carry;   // inclusive prefix over hist[1..x+1]
      if (x < (int)P){
        u32 r = 1u + cum;          // r_plus[x]
        float spv = sp[x];
        sumD   += (double)Dsh[x + r];
        sumSpr += (double)spv * (double)r;
        sumSp  += (double)spv;
      }
      carry += sc[1023];
      __syncthreads();
    }
    rd[tid]=sumD; __syncthreads();
    for (int off=512; off>0; off>>=1){ if (tid<off) rd[tid]+=rd[tid+off]; __syncthreads(); }
    double totD = rd[0]; __syncthreads();
    rd[tid]=sumSpr; __syncthreads();
    for (int off=512; off>0; off>>=1){ if (tid<off) rd[tid]+=rd[tid+off]; __syncthreads(); }
    double totSpr = rd[0]; __syncthreads();
    rd[tid]=sumSp; __syncthreads();
    for (int off=512; off>0; off>>=1){ if (tid<off) rd[tid]+=rd[tid+off]; __syncthreads(); }
    double totSp = rd[0];
    if (tid==0){
      double S1=0.0, S2=0.0;
      const double* pp = partials + (size_t)c*nblkM*2;
      for (int b=0;b<nblkM;b++){ S1+=pp[2*b]; S2+=pp[2*b+1]; }
      double Cc = Cconst[c];
      double Delta = 1.0 - totD/Cc;
      double Fp    = (double)(N+2u)*totSp - 2.0*totSpr;   // sum s_plus*c_plus
      double Fm    = (double)(P+2u)*S1   - 2.0*S2;        // sum s_minus*c_minus
      double Fstar = (double)N*totSp - (double)P*S1;
      myLoss = Delta + (Fp + Fm - Fstar)/((double)P*(double)N);
    }
  }
  if (tid==0){
    atomicExch(&classLoss[c], (u64)__double_as_longlong(myLoss));
    __threadfence();
    u32 old = atomicAdd(doneCount, 1u);
    if (old == (u32)gridDim.x - 1u){
      __threadfence();
      double s=0.0;
      for (int cc=0; cc<NC; ++cc){
        u64 bits = atomicAdd(&classLoss[cc], 0ull);  // coherent read
        s += __longlong_as_double((long long)bits);
      }
      out[0] = (float)(s/(double)NC);
    }
  }
}

extern "C" void kernel_launch(void* const* d_in, const int* in_sizes, int n_in,
                              void* d_out, int out_size, void* d_ws, size_t ws_size,
                              hipStream_t stream) {
  const float* scores = (const float*)d_in[0];
  const int*   labels = (const int*)d_in[1];
  int B  = in_sizes[1];
  int NC = in_sizes[0] / in_sizes[1];
  float* out = (float*)d_out;

  int SD = B + 8;            // per-copy stride of shifted D tables (16B-multiple)
  int strideAB = B + 8;      // per-class stride of A/B (16B-multiple, room for j=P and float4 tail)

  char* ws = (char*)d_ws;
  size_t off = 0;
  auto alloc = [&](size_t bytes)->char* {
    char* p = ws + off;
    off = (off + bytes + 255) & ~(size_t)255;
    return p;
  };
  float* Dsh = (float*)alloc((size_t)4*SD*4);
  // ---- zeroed region (must stay contiguous) ----
  char* zbeg = ws + off;
  u32* bhist     = (u32*)alloc((size_t)NC*2*NBUCKET*4);
  u32* Pcnt      = (u32*)alloc((size_t)NC*4);
  u32* optHist   = (u32*)alloc((size_t)NC*(B+2)*4);
  u32* doneCount = (u32*)alloc(4);
  char* zend = ws + off;
  // ----------------------------------------------
  u32* bstart    = (u32*)alloc((size_t)NC*2*(NBUCKET+1)*4);
  u32* bcursor   = (u32*)alloc((size_t)NC*2*NBUCKET*4);
  u64* keyArr    = (u64*)alloc((size_t)NC*2*B*8);
  float* sPos    = (float*)alloc((size_t)NC*B*4);
  float* sNeg    = (float*)alloc((size_t)NC*B*4);
  float* Aarr    = (float*)alloc((size_t)NC*strideAB*4);
  float* Barr    = (float*)alloc((size_t)NC*strideAB*4);
  double* Cconst = (double*)alloc((size_t)NC*8);
  int nblkM = (B + 255)/256;
  double* partials  = (double*)alloc((size_t)NC*nblkM*2*8);
  u64* classLoss    = (u64*)alloc((size_t)NC*8);

  hipMemsetAsync(zbeg, 0, (size_t)(zend - zbeg), stream);

  k_hist<<<(B*NC+255)/256, 256, 0, stream>>>(scores, labels, B, NC, bhist, Pcnt, Dsh, SD);
  k_scan<<<NC*2, 1024, 0, stream>>>(bhist, bstart, bcursor);
  k_scatter<<<(B*NC+255)/256, 256, 0, stream>>>(scores, labels, B, NC, bcursor, keyArr);
  k_rank<<<dim3((B+255)/256, NC*2), 256, 0, stream>>>(keyArr, bstart, Pcnt, B, sPos, sNeg);
  k_pre<<<NC, 1024, 0, stream>>>(sPos, Pcnt, Dsh, B, strideAB, Aarr, Barr, Cconst);
  k_main<<<dim3(nblkM, NC), 256, 0, stream>>>(sNeg, Pcnt, Dsh, SD, Aarr, Barr, B, strideAB, optHist, partials);
  k_finish<<<NC, 1024, 0, stream>>>(sPos, Pcnt, optHist, Dsh, Cconst, partials, B, nblkM, NC,
                                    classLoss, doneCount, out);
}